// Round 1
// baseline (178.209 us; speedup 1.0000x reference)
//
#include <hip/hip_runtime.h>
#include <hip/hip_bf16.h>
#include <math.h>

constexpr int T = 128;
constexpr int B = 128;
constexpr int R = 512;
constexpr int NS = 256;   // 2*T slots

// ---------------------------------------------------------------------------
// Kernel A: per-batch stack simulation.
// Block = one batch b (64 threads = 1 wave, lane holds 4 slots).
// For each t: push d1/d2, compute suffix-sums "used" (mass strictly above each
// slot, top = slot 255), record s (post-push) and used, then pop u_t of mass.
// ---------------------------------------------------------------------------
__global__ __launch_bounds__(64) void stack_sim(
    const float* __restrict__ u,    // [T][B]
    const float* __restrict__ d1,   // [T][B]
    const float* __restrict__ d2,   // [T][B]
    float* __restrict__ s_out,      // [T][B][NS]  (later overwritten with w)
    float* __restrict__ used_out)   // [T][B][NS]
{
    const int b    = blockIdx.x;
    const int lane = threadIdx.x;   // 0..63, owns slots 4*lane .. 4*lane+3

    float s0 = 0.f, s1 = 0.f, s2 = 0.f, s3 = 0.f;

    for (int t = 0; t < T; ++t) {
        const float d1v = d1[t * B + b];
        const float d2v = d2[t * B + b];
        const float uv  = u[t * B + b];

        // push: slots 2t (d1) and 2t+1 (d2) — both land in lane (2t)>>2
        const int slot = 2 * t;
        if (lane == (slot >> 2)) {
            if ((slot & 3) == 0) { s0 = d1v; s1 = d2v; }
            else                 { s2 = d1v; s3 = d2v; }
        }

        // local suffix sums (mass above slot, within this lane's 4 slots)
        const float ls3 = 0.f;
        const float ls2 = s3;
        const float ls1 = s3 + s2;
        const float ls0 = ls1 + s1;
        const float chunk = ls0 + s0;

        // inclusive suffix scan of chunk over lanes (sum over lanes >= me)
        float suf = chunk;
        #pragma unroll
        for (int off = 1; off < 64; off <<= 1) {
            float o = __shfl_down(suf, off);
            if (lane + off < 64) suf += o;
        }
        const float above = suf - chunk;   // mass in lanes strictly above me

        const float u0 = above + ls0;
        const float u1 = above + ls1;
        const float u2 = above + ls2;
        const float u3 = above + ls3;

        const size_t base = ((size_t)t * B + b) * NS + 4 * lane;
        *(float4*)(s_out + base)    = make_float4(s0, s1, s2, s3);
        *(float4*)(used_out + base) = make_float4(u0, u1, u2, u3);

        // pop: s -= min(s, max(0, u_t - used))   (matches reference pop_step)
        s0 = s0 - fminf(s0, fmaxf(0.f, uv - u0));
        s1 = s1 - fminf(s1, fmaxf(0.f, uv - u1));
        s2 = s2 - fminf(s2, fmaxf(0.f, uv - u2));
        s3 = s3 - fminf(s3, fmaxf(0.f, uv - u3));
    }
}

// ---------------------------------------------------------------------------
// Kernel B: scal[t,j] = max_b (u[t,b] - used[t,b,j])  (scalar across batch!)
// then overwrite s with w = min(s, scal).
// Block = one t, thread = slot j; b-loop coalesced across threads.
// ---------------------------------------------------------------------------
__global__ __launch_bounds__(256) void scal_w(
    const float* __restrict__ u,     // [T][B]
    float* __restrict__ s_w,         // [T][B][NS]: in s, out w
    const float* __restrict__ used)  // [T][B][NS]
{
    const int t = blockIdx.x;
    const int j = threadIdx.x;
    const float* up = u + (size_t)t * B;
    const size_t base = (size_t)t * B * NS + j;

    float m0 = -INFINITY, m1 = -INFINITY, m2 = -INFINITY, m3 = -INFINITY;
    #pragma unroll 4
    for (int b = 0; b < B; b += 4) {
        m0 = fmaxf(m0, up[b + 0] - used[base + (size_t)(b + 0) * NS]);
        m1 = fmaxf(m1, up[b + 1] - used[base + (size_t)(b + 1) * NS]);
        m2 = fmaxf(m2, up[b + 2] - used[base + (size_t)(b + 2) * NS]);
        m3 = fmaxf(m3, up[b + 3] - used[base + (size_t)(b + 3) * NS]);
    }
    const float m = fmaxf(fmaxf(m0, m1), fmaxf(m2, m3));

    #pragma unroll 4
    for (int b = 0; b < B; ++b) {
        const size_t idx = base + (size_t)b * NS;
        s_w[idx] = fminf(s_w[idx], m);
    }
}

// ---------------------------------------------------------------------------
// Kernel C: batched GEMM. Out[t,b,r] = sum_j w[t,b,j] * V[j,b,r],
// V[j,b,r] = (j odd ? v2 : v1)[j>>1, b, r].
// Grid = (b, r-tile of 128). Block 256 threads, thread = 8t x 8r outputs.
// ---------------------------------------------------------------------------
#define RT 128
__global__ __launch_bounds__(256) void gemm_out(
    const float* __restrict__ w,    // [T][B][NS]
    const float* __restrict__ v1,   // [T][B][R]
    const float* __restrict__ v2,   // [T][B][R]
    float* __restrict__ out)        // [T][B][R]
{
    const int b  = blockIdx.x;
    const int r0 = blockIdx.y * RT;

    __shared__ float wT[32][132];   // [j within chunk][t], padded (+4)
    __shared__ float vT[32][RT];    // [j within chunk][r]

    const int tid = threadIdx.x;
    const int tx  = tid & 15;       // r: {r0+tx*4..+3} and {r0+64+tx*4..+3}
    const int ty  = tid >> 4;       // t: ty*8 .. ty*8+7

    float acc[8][8];
    #pragma unroll
    for (int i = 0; i < 8; ++i)
        #pragma unroll
        for (int q = 0; q < 8; ++q) acc[i][q] = 0.f;

    for (int jc = 0; jc < NS; jc += 32) {
        // stage wT (transposed): 128 t x 32 j = 4096 floats
        #pragma unroll
        for (int k = 0; k < 4; ++k) {
            const int p  = tid + 256 * k;
            const int t  = p >> 3;
            const int jq = p & 7;
            float4 wv = *(const float4*)(w + ((size_t)t * B + b) * NS + jc + jq * 4);
            wT[jq * 4 + 0][t] = wv.x;
            wT[jq * 4 + 1][t] = wv.y;
            wT[jq * 4 + 2][t] = wv.z;
            wT[jq * 4 + 3][t] = wv.w;
        }
        // stage vT: 32 j x 128 r
        #pragma unroll
        for (int k = 0; k < 4; ++k) {
            const int p    = tid + 256 * k;
            const int jj   = p >> 5;
            const int rq   = p & 31;
            const int slot = jc + jj;
            const float* vsrc = (slot & 1) ? v2 : v1;
            float4 vv = *(const float4*)(vsrc + ((size_t)(slot >> 1) * B + b) * R + r0 + rq * 4);
            *(float4*)(&vT[jj][rq * 4]) = vv;
        }
        __syncthreads();

        for (int jj = 0; jj < 32; ++jj) {
            float wv[8], vv[8];
            *(float4*)(wv + 0) = *(const float4*)(&wT[jj][ty * 8]);
            *(float4*)(wv + 4) = *(const float4*)(&wT[jj][ty * 8 + 4]);
            *(float4*)(vv + 0) = *(const float4*)(&vT[jj][tx * 4]);
            *(float4*)(vv + 4) = *(const float4*)(&vT[jj][64 + tx * 4]);
            #pragma unroll
            for (int i = 0; i < 8; ++i)
                #pragma unroll
                for (int q = 0; q < 8; ++q)
                    acc[i][q] += wv[i] * vv[q];
        }
        __syncthreads();
    }

    // write: t = ty*8+i, r = r0 + tx*4 (+0..3) and r0 + 64 + tx*4 (+0..3)
    #pragma unroll
    for (int i = 0; i < 8; ++i) {
        const int t = ty * 8 + i;
        float* dst = out + ((size_t)t * B + b) * R + r0;
        *(float4*)(dst + tx * 4)      = *(float4*)(&acc[i][0]);
        *(float4*)(dst + 64 + tx * 4) = *(float4*)(&acc[i][4]);
    }
}

extern "C" void kernel_launch(void* const* d_in, const int* in_sizes, int n_in,
                              void* d_out, int out_size, void* d_ws, size_t ws_size,
                              hipStream_t stream) {
    const float* u  = (const float*)d_in[0];
    const float* d1 = (const float*)d_in[1];
    const float* d2 = (const float*)d_in[2];
    const float* v1 = (const float*)d_in[3];
    const float* v2 = (const float*)d_in[4];
    float* out = (float*)d_out;

    const size_t elems = (size_t)T * B * NS;       // 8.39M floats
    const size_t bytes = elems * sizeof(float);    // 16.78 MB

    float* s_w;
    float* used;
    if (ws_size >= 2 * bytes) {
        s_w  = (float*)d_ws;
        used = (float*)d_ws + elems;
    } else {
        // fall back: park `used` in d_out (33.5 MB, dead until kernel C writes it)
        s_w  = (float*)d_ws;
        used = (float*)d_out;
    }

    stack_sim<<<dim3(B), dim3(64), 0, stream>>>(u, d1, d2, s_w, used);
    scal_w<<<dim3(T), dim3(256), 0, stream>>>(u, s_w, used);
    gemm_out<<<dim3(B, R / RT), dim3(256), 0, stream>>>(s_w, v1, v2, out);
}

// Round 2
// 135.323 us; speedup vs baseline: 1.3169x; 1.3169x over previous
//
#include <hip/hip_runtime.h>
#include <hip/hip_bf16.h>
#include <math.h>

constexpr int T = 128;
constexpr int B = 128;
constexpr int R = 512;
constexpr int NS = 256;   // 2*T slots

// ---------------------------------------------------------------------------
// Kernel 1: per-batch stack level recurrence.
// H_t = max(0, H_{t-1} + d1_t + d2_t - u_t).  128 threads total (coalesced).
// ---------------------------------------------------------------------------
__global__ __launch_bounds__(64) void level_scan(
    const float* __restrict__ u, const float* __restrict__ d1,
    const float* __restrict__ d2, float* __restrict__ H)
{
    const int b = blockIdx.x * 64 + threadIdx.x;
    float h = 0.f;
    for (int t = 0; t < T; ++t) {
        h = fmaxf(0.f, h + d1[t * B + b] + d2[t * B + b] - u[t * B + b]);
        H[t * B + b] = h;
    }
}

// ---------------------------------------------------------------------------
// Kernel 2: closed-form weights.
// Block = one t, 64 lanes, lane owns batches (lane, lane+64).
// Backward scan p = t..0 keeps m = min_{tau in [p, t-1]} H_tau per batch:
//   base(2p) = H_{p-1}; s = clamp(m - base, 0, d); used = H'_t - min(top, m)
//   scal(slot) = max_b (u_t - used)   [cross-lane shfl_xor max, 128 batches]
//   w = min(s, scal);  slots > 2t+1 are zero.
// Writes w[t][b][slot] as float4 (pairs of p-iterations). No `used` tensor.
// ---------------------------------------------------------------------------
__global__ __launch_bounds__(64) void weights(
    const float* __restrict__ u, const float* __restrict__ d1,
    const float* __restrict__ d2, const float* __restrict__ H,
    float* __restrict__ w)
{
    const int t    = blockIdx.x;
    const int lane = threadIdx.x;
    const int b0   = lane;
    const int b1   = lane + 64;

    const float Ht1a = (t > 0) ? H[(t - 1) * B + b0] : 0.f;
    const float Ht1b = (t > 0) ? H[(t - 1) * B + b1] : 0.f;
    const float Hpa  = Ht1a + d1[t * B + b0] + d2[t * B + b0];  // H'_t
    const float Hpb  = Ht1b + d1[t * B + b1] + d2[t * B + b1];
    const float Aa   = u[t * B + b0] - Hpa;
    const float Ab   = u[t * B + b1] - Hpb;

    float ma = 1e30f, mb = 1e30f;      // running suffix-min of H over [p, t-1]
    float ca = Ht1a, cb = Ht1b;        // carry: H[p] for the next iteration
    float s2a = 0.f, s3a = 0.f, s2b = 0.f, s3b = 0.f;  // stash elems 2,3 of group

    float* wrow0 = w + ((size_t)t * B + b0) * NS;
    float* wrow1 = w + ((size_t)t * B + b1) * NS;

    for (int p = t; p >= 0; --p) {
        if (p < t) { ma = fminf(ma, ca); mb = fminf(mb, cb); }

        const float basea = (p > 0) ? H[(p - 1) * B + b0] : 0.f;  // H_{p-1}
        const float baseb = (p > 0) ? H[(p - 1) * B + b1] : 0.f;
        const float d1a = d1[p * B + b0], d1b = d1[p * B + b1];
        const float d2a = d2[p * B + b0], d2b = d2[p * B + b1];
        const float top0a = basea + d1a, top0b = baseb + d1b;   // top of slot 2p
        const float top1a = top0a + d2a, top1b = top0b + d2b;   // top of slot 2p+1

        // s at read time
        const float sa0 = fminf(fmaxf(ma - basea, 0.f), d1a);
        const float sb0 = fminf(fmaxf(mb - baseb, 0.f), d1b);
        const float sa1 = fminf(fmaxf(ma - top0a, 0.f), d2a);
        const float sb1 = fminf(fmaxf(mb - top0b, 0.f), d2b);

        // scal = max_b (u - used) = max_b (A + min(top, m))
        float cand0 = fmaxf(Aa + fminf(top0a, ma), Ab + fminf(top0b, mb));
        float cand1 = fmaxf(Aa + fminf(top1a, ma), Ab + fminf(top1b, mb));
        #pragma unroll
        for (int off = 32; off >= 1; off >>= 1) {
            cand0 = fmaxf(cand0, __shfl_xor(cand0, off));
            cand1 = fmaxf(cand1, __shfl_xor(cand1, off));
        }

        const float w0a = fminf(sa0, cand0), w0b = fminf(sb0, cand0);
        const float w1a = fminf(sa1, cand1), w1b = fminf(sb1, cand1);

        if (p & 1) {                    // slots 2p,2p+1 are elems 2,3 of group p>>1
            s2a = w0a; s3a = w1a; s2b = w0b; s3b = w1b;
        } else {                        // elems 0,1 of group p>>1 -> store
            const int g = p >> 1;
            *(float4*)(wrow0 + 4 * g) = make_float4(w0a, w1a, s2a, s3a);
            *(float4*)(wrow1 + 4 * g) = make_float4(w0b, w1b, s2b, s3b);
        }
        ca = basea; cb = baseb;
    }

    // zero-fill never-pushed slots (reference gives w=0 there since max_b u >= 0)
    const float4 z = make_float4(0.f, 0.f, 0.f, 0.f);
    for (int g = (t >> 1) + 1; g < NS / 4; ++g) {
        *(float4*)(wrow0 + 4 * g) = z;
        *(float4*)(wrow1 + 4 * g) = z;
    }
}

// ---------------------------------------------------------------------------
// Kernel 3: batched GEMM. Out[t,b,r] = sum_j w[t,b,j] * V[j,b,r],
// V[j,b,r] = (j odd ? v2 : v1)[j>>1, b, r].   (unchanged from round 1)
// ---------------------------------------------------------------------------
#define RT 128
__global__ __launch_bounds__(256) void gemm_out(
    const float* __restrict__ w,    // [T][B][NS]
    const float* __restrict__ v1,   // [T][B][R]
    const float* __restrict__ v2,   // [T][B][R]
    float* __restrict__ out)        // [T][B][R]
{
    const int b  = blockIdx.x;
    const int r0 = blockIdx.y * RT;

    __shared__ float wT[32][132];   // [j within chunk][t], padded (+4)
    __shared__ float vT[32][RT];    // [j within chunk][r]

    const int tid = threadIdx.x;
    const int tx  = tid & 15;
    const int ty  = tid >> 4;

    float acc[8][8];
    #pragma unroll
    for (int i = 0; i < 8; ++i)
        #pragma unroll
        for (int q = 0; q < 8; ++q) acc[i][q] = 0.f;

    for (int jc = 0; jc < NS; jc += 32) {
        #pragma unroll
        for (int k = 0; k < 4; ++k) {
            const int p  = tid + 256 * k;
            const int t  = p >> 3;
            const int jq = p & 7;
            float4 wv = *(const float4*)(w + ((size_t)t * B + b) * NS + jc + jq * 4);
            wT[jq * 4 + 0][t] = wv.x;
            wT[jq * 4 + 1][t] = wv.y;
            wT[jq * 4 + 2][t] = wv.z;
            wT[jq * 4 + 3][t] = wv.w;
        }
        #pragma unroll
        for (int k = 0; k < 4; ++k) {
            const int p    = tid + 256 * k;
            const int jj   = p >> 5;
            const int rq   = p & 31;
            const int slot = jc + jj;
            const float* vsrc = (slot & 1) ? v2 : v1;
            float4 vv = *(const float4*)(vsrc + ((size_t)(slot >> 1) * B + b) * R + r0 + rq * 4);
            *(float4*)(&vT[jj][rq * 4]) = vv;
        }
        __syncthreads();

        for (int jj = 0; jj < 32; ++jj) {
            float wv[8], vv[8];
            *(float4*)(wv + 0) = *(const float4*)(&wT[jj][ty * 8]);
            *(float4*)(wv + 4) = *(const float4*)(&wT[jj][ty * 8 + 4]);
            *(float4*)(vv + 0) = *(const float4*)(&vT[jj][tx * 4]);
            *(float4*)(vv + 4) = *(const float4*)(&vT[jj][64 + tx * 4]);
            #pragma unroll
            for (int i = 0; i < 8; ++i)
                #pragma unroll
                for (int q = 0; q < 8; ++q)
                    acc[i][q] += wv[i] * vv[q];
        }
        __syncthreads();
    }

    #pragma unroll
    for (int i = 0; i < 8; ++i) {
        const int t = ty * 8 + i;
        float* dst = out + ((size_t)t * B + b) * R + r0;
        *(float4*)(dst + tx * 4)      = *(float4*)(&acc[i][0]);
        *(float4*)(dst + 64 + tx * 4) = *(float4*)(&acc[i][4]);
    }
}

extern "C" void kernel_launch(void* const* d_in, const int* in_sizes, int n_in,
                              void* d_out, int out_size, void* d_ws, size_t ws_size,
                              hipStream_t stream) {
    const float* u  = (const float*)d_in[0];
    const float* d1 = (const float*)d_in[1];
    const float* d2 = (const float*)d_in[2];
    const float* v1 = (const float*)d_in[3];
    const float* v2 = (const float*)d_in[4];
    float* out = (float*)d_out;

    const size_t elems = (size_t)T * B * NS;          // 8.39M floats (w)
    float* w = (float*)d_ws;
    float* H;
    if (ws_size >= (elems + (size_t)T * B) * sizeof(float)) {
        H = (float*)d_ws + elems;
    } else {
        // H (64 KB) parked at start of d_out; dead before gemm_out writes out.
        H = (float*)d_out;
    }

    level_scan<<<dim3(2), dim3(64), 0, stream>>>(u, d1, d2, H);
    weights<<<dim3(T), dim3(64), 0, stream>>>(u, d1, d2, H, w);
    gemm_out<<<dim3(B, R / RT), dim3(256), 0, stream>>>(w, v1, v2, out);
}

// Round 3
// 56.653 us; speedup vs baseline: 3.1456x; 2.3886x over previous
//
#include <hip/hip_runtime.h>
#include <hip/hip_bf16.h>
#include <math.h>

constexpr int T = 128;
constexpr int B = 128;
constexpr int R = 512;
constexpr int NS = 256;   // 2*T slots

typedef __attribute__((ext_vector_type(8))) short bf16x8;
typedef __attribute__((ext_vector_type(4))) float f32x4;

static __device__ __forceinline__ ushort f2bf(float f) {
    union { float f; unsigned u; } v; v.f = f;
    unsigned r = v.u + 0x7fffu + ((v.u >> 16) & 1u);   // RNE
    return (ushort)(r >> 16);
}

// ---------------------------------------------------------------------------
// Kernel 1: weights (H fused). Block = one t, 256 threads (4 waves).
// Phase A: threads 0..127 compute H recurrence into LDS.
// Phase B: wave w owns p in [32w, min(32w+31,t)]; suffix-min m seeded from a
//          LDS boundary scan, then <=32 sequential iterations with 64-lane
//          shfl_xor max for scal. Lane owns batches (lane, lane+64).
// Phase C: zero-fill never-pushed slot groups.
// ---------------------------------------------------------------------------
__global__ __launch_bounds__(256) void weights(
    const float* __restrict__ u, const float* __restrict__ d1,
    const float* __restrict__ d2, float* __restrict__ w)
{
    const int t    = blockIdx.x;
    const int tid  = threadIdx.x;
    const int wv   = tid >> 6;
    const int lane = tid & 63;
    __shared__ float Hs[T][B];   // 64 KB

    if (tid < B) {               // Phase A
        const int b = tid;
        float h = 0.f;
        for (int tt = 0; tt < t; ++tt) {
            h = fmaxf(0.f, h + d1[tt*B+b] + d2[tt*B+b] - u[tt*B+b]);
            Hs[tt][b] = h;
        }
    }
    __syncthreads();

    const int b0 = lane, b1 = lane + 64;
    const float Ht1a = (t > 0) ? Hs[t-1][b0] : 0.f;
    const float Ht1b = (t > 0) ? Hs[t-1][b1] : 0.f;
    const float Hpa  = Ht1a + d1[t*B+b0] + d2[t*B+b0];   // H'_t
    const float Hpb  = Ht1b + d1[t*B+b1] + d2[t*B+b1];
    const float Aa   = u[t*B+b0] - Hpa;
    const float Ab   = u[t*B+b1] - Hpb;

    float* wrow0 = w + ((size_t)t * B + b0) * NS;
    float* wrow1 = w + ((size_t)t * B + b1) * NS;

    const int plo = wv * 32;
    if (plo <= t) {
        const int pe = min(plo + 31, t);
        float ma = 1e30f, mb = 1e30f;
        for (int tau = plo + 32; tau <= t - 1; ++tau) {    // boundary min
            ma = fminf(ma, Hs[tau][b0]);
            mb = fminf(mb, Hs[tau][b1]);
        }
        float s2a = 0.f, s3a = 0.f, s2b = 0.f, s3b = 0.f;
        for (int p = pe; p >= plo; --p) {
            if (p < t) { ma = fminf(ma, Hs[p][b0]); mb = fminf(mb, Hs[p][b1]); }
            const float basea = (p > 0) ? Hs[p-1][b0] : 0.f;
            const float baseb = (p > 0) ? Hs[p-1][b1] : 0.f;
            const float d1a = d1[p*B+b0], d1b = d1[p*B+b1];
            const float d2a = d2[p*B+b0], d2b = d2[p*B+b1];
            const float top0a = basea + d1a, top0b = baseb + d1b;
            const float top1a = top0a + d2a, top1b = top0b + d2b;

            const float sa0 = fminf(fmaxf(ma - basea, 0.f), d1a);
            const float sb0 = fminf(fmaxf(mb - baseb, 0.f), d1b);
            const float sa1 = fminf(fmaxf(ma - top0a, 0.f), d2a);
            const float sb1 = fminf(fmaxf(mb - top0b, 0.f), d2b);

            float cand0 = fmaxf(Aa + fminf(top0a, ma), Ab + fminf(top0b, mb));
            float cand1 = fmaxf(Aa + fminf(top1a, ma), Ab + fminf(top1b, mb));
            #pragma unroll
            for (int off = 32; off >= 1; off >>= 1) {
                cand0 = fmaxf(cand0, __shfl_xor(cand0, off));
                cand1 = fmaxf(cand1, __shfl_xor(cand1, off));
            }

            const float w0a = fminf(sa0, cand0), w0b = fminf(sb0, cand0);
            const float w1a = fminf(sa1, cand1), w1b = fminf(sb1, cand1);
            if (p & 1) { s2a = w0a; s3a = w1a; s2b = w0b; s3b = w1b; }
            else {
                const int g = p >> 1;
                *(float4*)(wrow0 + 4*g) = make_float4(w0a, w1a, s2a, s3a);
                *(float4*)(wrow1 + 4*g) = make_float4(w0b, w1b, s2b, s3b);
            }
        }
    }

    const int gstart = (t >> 1) + 1;                 // Phase C
    const int ng = (NS / 4) - gstart;
    if (ng > 0) {
        const float4 z = make_float4(0.f, 0.f, 0.f, 0.f);
        const int total = ng * B;
        for (int idx = tid; idx < total; idx += 256) {
            const int gi = idx % ng;
            const int bb = idx / ng;
            *(float4*)(w + ((size_t)t*B + bb)*NS + 4*(gstart + gi)) = z;
        }
    }
}

// ---------------------------------------------------------------------------
// Kernel 2: bf16 MFMA GEMM. Out[t,b,r] = sum_j w[t,b,j] * V[j,b,r],
// V interleaved from v1/v2. Block = (b, r-tile 128), 256 thr = 4 waves.
// Wave w computes t-rows [32w,32w+32) x 128 r via 2x8 16x16x32 frags.
// K chunks of 32 double-buffered; stage split load-early/write-late.
// ---------------------------------------------------------------------------
__global__ __launch_bounds__(256) void gemm_mfma(
    const float* __restrict__ w, const float* __restrict__ v1,
    const float* __restrict__ v2, float* __restrict__ out)
{
    const int b   = blockIdx.x;
    const int r0  = blockIdx.y * 128;
    const int tid = threadIdx.x;
    const int wv  = tid >> 6;
    const int lane = tid & 63;

    __shared__ ushort As[2][128][40];   // [t][j] bf16, pitch 40 (80 B, 16B-aligned)
    __shared__ ushort Bs[2][128][40];   // [r][j] bf16 (V transposed)

    // A staging: thread = (row, j-half)
    const int arow = tid >> 1;
    const int ajh  = (tid & 1) * 16;
    const float* abase = w + ((size_t)arow * B + b) * NS + ajh;

    // B staging: thread = (slot-pair p2, r-oct ro)
    const int p2 = tid & 15;
    const int ro = tid >> 4;
    const int rr = r0 + ro * 8;

    f32x4 acc0[8], acc1[8];
    const f32x4 zz = {0.f, 0.f, 0.f, 0.f};
    #pragma unroll
    for (int i = 0; i < 8; ++i) { acc0[i] = zz; acc1[i] = zz; }

    float4 la[4], lv1[2], lv2[2];

    #define STAGE_LOAD(c) do {                                          \
        const float* ap_ = abase + (c) * 32;                            \
        la[0] = *(const float4*)(ap_ + 0);                              \
        la[1] = *(const float4*)(ap_ + 4);                              \
        la[2] = *(const float4*)(ap_ + 8);                              \
        la[3] = *(const float4*)(ap_ + 12);                             \
        const int pg_ = (c) * 16 + p2;                                  \
        const float* q1_ = v1 + ((size_t)pg_ * B + b) * R + rr;         \
        const float* q2_ = v2 + ((size_t)pg_ * B + b) * R + rr;         \
        lv1[0] = *(const float4*)(q1_ + 0);                             \
        lv1[1] = *(const float4*)(q1_ + 4);                             \
        lv2[0] = *(const float4*)(q2_ + 0);                             \
        lv2[1] = *(const float4*)(q2_ + 4);                             \
    } while (0)

    #define STAGE_WRITE(buf) do {                                       \
        ushort aw_[16];                                                 \
        const float* lf_ = (const float*)la;                            \
        _Pragma("unroll")                                               \
        for (int i_ = 0; i_ < 16; ++i_) aw_[i_] = f2bf(lf_[i_]);        \
        *(bf16x8*)&As[buf][arow][ajh]     = *(bf16x8*)&aw_[0];          \
        *(bf16x8*)&As[buf][arow][ajh + 8] = *(bf16x8*)&aw_[8];          \
        const float* f1_ = (const float*)lv1;                           \
        const float* f2_ = (const float*)lv2;                           \
        _Pragma("unroll")                                               \
        for (int i_ = 0; i_ < 8; ++i_) {                                \
            unsigned pk_ = (unsigned)f2bf(f1_[i_]) |                    \
                           ((unsigned)f2bf(f2_[i_]) << 16);             \
            *(unsigned*)&Bs[buf][ro*8 + i_][p2*2] = pk_;                \
        }                                                               \
    } while (0)

    const int tb = wv * 32 + (lane & 15);
    const int ko = (lane >> 4) * 8;

    STAGE_LOAD(0);
    STAGE_WRITE(0);
    #pragma unroll
    for (int c = 0; c < 8; ++c) {
        const int buf = c & 1;
        if (c < 7) STAGE_LOAD(c + 1);
        __syncthreads();
        bf16x8 a0 = *(const bf16x8*)&As[buf][tb][ko];
        bf16x8 a1 = *(const bf16x8*)&As[buf][tb + 16][ko];
        #pragma unroll
        for (int cf = 0; cf < 8; ++cf) {
            bf16x8 bb = *(const bf16x8*)&Bs[buf][cf*16 + (lane & 15)][ko];
            acc0[cf] = __builtin_amdgcn_mfma_f32_16x16x32_bf16(a0, bb, acc0[cf], 0, 0, 0);
            acc1[cf] = __builtin_amdgcn_mfma_f32_16x16x32_bf16(a1, bb, acc1[cf], 0, 0, 0);
        }
        if (c < 7) STAGE_WRITE((c + 1) & 1);
    }

    // epilogue: D col = lane&15 (r), row = (lane>>4)*4 + i (t)
    const int dcol  = lane & 15;
    const int drow4 = (lane >> 4) * 4;
    #pragma unroll
    for (int cf = 0; cf < 8; ++cf) {
        const int rg = r0 + cf * 16 + dcol;
        #pragma unroll
        for (int i = 0; i < 4; ++i) {
            const int tg0 = wv * 32 + drow4 + i;
            const int tg1 = tg0 + 16;
            out[((size_t)tg0 * B + b) * R + rg] = acc0[cf][i];
            out[((size_t)tg1 * B + b) * R + rg] = acc1[cf][i];
        }
    }
    #undef STAGE_LOAD
    #undef STAGE_WRITE
}

extern "C" void kernel_launch(void* const* d_in, const int* in_sizes, int n_in,
                              void* d_out, int out_size, void* d_ws, size_t ws_size,
                              hipStream_t stream) {
    const float* u  = (const float*)d_in[0];
    const float* d1 = (const float*)d_in[1];
    const float* d2 = (const float*)d_in[2];
    const float* v1 = (const float*)d_in[3];
    const float* v2 = (const float*)d_in[4];
    float* out = (float*)d_out;
    float* w   = (float*)d_ws;          // 16.78 MB

    weights<<<dim3(T), dim3(256), 0, stream>>>(u, d1, d2, w);
    // grid x = b (fastest) -> same-b r-tiles land on the same XCD (id % 8 == b % 8)
    gemm_mfma<<<dim3(B, R / 128), dim3(256), 0, stream>>>(w, v1, v2, out);
}

// Round 4
// 51.919 us; speedup vs baseline: 3.4325x; 1.0912x over previous
//
#include <hip/hip_runtime.h>
#include <hip/hip_bf16.h>
#include <math.h>

constexpr int T = 128;
constexpr int B = 128;
constexpr int R = 512;
constexpr int NS = 256;   // 2*T slots

typedef __attribute__((ext_vector_type(8))) short bf16x8;
typedef __attribute__((ext_vector_type(4))) float f32x4;

static __device__ __forceinline__ ushort f2bf(float f) {
    union { float f; unsigned u; } v; v.f = f;
    unsigned r = v.u + 0x7fffu + ((v.u >> 16) & 1u);   // RNE
    return (ushort)(r >> 16);
}

// ---------------------------------------------------------------------------
// Kernel 1: closed-form weights, bf16 output. Block = one t, 256 threads.
// Phase A0: coalesced stage e = d1+d2-u rows [0,t) into LDS (float4).
// Phase A1: threads 0..127 run H chain from LDS, overwrite e with H in place.
// Phase B : wave wv owns p in [32wv, min(32wv+31,t)]; per-batch suffix-min m
//           from LDS; 64-lane shfl_xor max for scal; d1/d2 rows prefetched.
// Phase C : zero-fill never-pushed slot groups (bf16 zeros).
// ---------------------------------------------------------------------------
__global__ __launch_bounds__(256) void weights(
    const float* __restrict__ u, const float* __restrict__ d1,
    const float* __restrict__ d2, ushort* __restrict__ w)
{
    const int t    = blockIdx.x;
    const int tid  = threadIdx.x;
    const int wv   = tid >> 6;
    const int lane = tid & 63;
    __shared__ float eH[T][B];   // 64 KB: e, overwritten with H

    // Phase A0: stage e rows [0, t)
    const int nfl = t * B;
    for (int i = tid * 4; i < nfl; i += 1024) {
        const float4 a  = *(const float4*)(d1 + i);
        const float4 b4 = *(const float4*)(d2 + i);
        const float4 c4 = *(const float4*)(u + i);
        *(float4*)(&eH[0][0] + i) =
            make_float4(a.x + b4.x - c4.x, a.y + b4.y - c4.y,
                        a.z + b4.z - c4.z, a.w + b4.w - c4.w);
    }
    __syncthreads();

    // Phase A1: H recurrence (in place)
    if (tid < B) {
        float h = 0.f;
        #pragma unroll 4
        for (int tt = 0; tt < t; ++tt) {
            h = fmaxf(0.f, h + eH[tt][tid]);
            eH[tt][tid] = h;
        }
    }
    __syncthreads();

    const int b0 = lane, b1 = lane + 64;
    const float Ht1a = (t > 0) ? eH[t-1][b0] : 0.f;
    const float Ht1b = (t > 0) ? eH[t-1][b1] : 0.f;
    const float Hpa  = Ht1a + d1[t*B+b0] + d2[t*B+b0];   // H'_t
    const float Hpb  = Ht1b + d1[t*B+b1] + d2[t*B+b1];
    const float Aa   = u[t*B+b0] - Hpa;
    const float Ab   = u[t*B+b1] - Hpb;

    ushort* wrow0 = w + ((size_t)t * B + b0) * NS;
    ushort* wrow1 = w + ((size_t)t * B + b1) * NS;

    const int plo = wv * 32;
    if (plo <= t) {
        const int pe = min(plo + 31, t);
        float ma = 1e30f, mb = 1e30f;
        for (int tau = plo + 32; tau <= t - 1; ++tau) {    // boundary min
            ma = fminf(ma, eH[tau][b0]);
            mb = fminf(mb, eH[tau][b1]);
        }
        float s2a = 0.f, s3a = 0.f, s2b = 0.f, s3b = 0.f;
        float nd1a = d1[pe*B+b0], nd1b = d1[pe*B+b1];
        float nd2a = d2[pe*B+b0], nd2b = d2[pe*B+b1];
        for (int p = pe; p >= plo; --p) {
            const float d1a = nd1a, d1b = nd1b, d2a = nd2a, d2b = nd2b;
            if (p > plo) {      // prefetch next iteration's rows
                nd1a = d1[(p-1)*B+b0]; nd1b = d1[(p-1)*B+b1];
                nd2a = d2[(p-1)*B+b0]; nd2b = d2[(p-1)*B+b1];
            }
            if (p < t) { ma = fminf(ma, eH[p][b0]); mb = fminf(mb, eH[p][b1]); }
            const float basea = (p > 0) ? eH[p-1][b0] : 0.f;
            const float baseb = (p > 0) ? eH[p-1][b1] : 0.f;
            const float top0a = basea + d1a, top0b = baseb + d1b;
            const float top1a = top0a + d2a, top1b = top0b + d2b;

            const float sa0 = fminf(fmaxf(ma - basea, 0.f), d1a);
            const float sb0 = fminf(fmaxf(mb - baseb, 0.f), d1b);
            const float sa1 = fminf(fmaxf(ma - top0a, 0.f), d2a);
            const float sb1 = fminf(fmaxf(mb - top0b, 0.f), d2b);

            float cand0 = fmaxf(Aa + fminf(top0a, ma), Ab + fminf(top0b, mb));
            float cand1 = fmaxf(Aa + fminf(top1a, ma), Ab + fminf(top1b, mb));
            #pragma unroll
            for (int off = 32; off >= 1; off >>= 1) {
                cand0 = fmaxf(cand0, __shfl_xor(cand0, off));
                cand1 = fmaxf(cand1, __shfl_xor(cand1, off));
            }

            const float w0a = fminf(sa0, cand0), w0b = fminf(sb0, cand0);
            const float w1a = fminf(sa1, cand1), w1b = fminf(sb1, cand1);
            if (p & 1) { s2a = w0a; s3a = w1a; s2b = w0b; s3b = w1b; }
            else {
                const int g = p >> 1;
                *(ushort4*)(wrow0 + 4*g) =
                    make_ushort4(f2bf(w0a), f2bf(w1a), f2bf(s2a), f2bf(s3a));
                *(ushort4*)(wrow1 + 4*g) =
                    make_ushort4(f2bf(w0b), f2bf(w1b), f2bf(s2b), f2bf(s3b));
            }
        }
    }

    // Phase C: zero-fill never-pushed groups
    const int gstart = (t >> 1) + 1;
    const int ng = (NS / 4) - gstart;
    if (ng > 0) {
        const ushort4 z = make_ushort4(0, 0, 0, 0);
        const int total = ng * B;
        for (int idx = tid; idx < total; idx += 256) {
            const int gi = idx % ng;
            const int bb = idx / ng;
            *(ushort4*)(w + ((size_t)t*B + bb)*NS + 4*(gstart + gi)) = z;
        }
    }
}

// ---------------------------------------------------------------------------
// Kernel 2: bf16 MFMA GEMM. Out[t,b,r] = sum_j w[t,b,j] * V[j,b,r],
// V interleaved from v1/v2 (fp32 -> bf16 at stage). A (w) is already bf16.
// Block = (b, r-tile 128), 256 thr = 4 waves; wave wv owns t in [32wv,32wv+32).
// Zero-structure: slot j is zero for t < j/2 -> wave wv skips chunk c>2wv+1;
// A-stage threads with arow<16c write zeros instead of loading.
// ---------------------------------------------------------------------------
__global__ __launch_bounds__(256) void gemm_mfma(
    const ushort* __restrict__ w, const float* __restrict__ v1,
    const float* __restrict__ v2, float* __restrict__ out)
{
    const int b    = blockIdx.x;
    const int r0   = blockIdx.y * 128;
    const int tid  = threadIdx.x;
    const int wv   = tid >> 6;
    const int lane = tid & 63;

    __shared__ ushort As[2][128][40];   // [t][j] bf16, pitch 40
    __shared__ ushort Bs[2][128][40];   // [r][j] bf16 (V transposed)

    const int arow = tid >> 1;          // A: two threads per t-row
    const int ajh  = (tid & 1) * 16;
    const ushort* abase = w + ((size_t)arow * B + b) * NS + ajh;

    const int p2 = tid & 15;            // B: slot-pair, r-oct
    const int ro = tid >> 4;
    const int rr = r0 + ro * 8;

    f32x4 acc0[8], acc1[8];
    const f32x4 zz = {0.f, 0.f, 0.f, 0.f};
    #pragma unroll
    for (int i = 0; i < 8; ++i) { acc0[i] = zz; acc1[i] = zz; }

    uint4 la0, la1;
    float4 lv1[2], lv2[2];

    #define STAGE_LOAD(c) do {                                          \
        if (arow >= 16 * (c)) {                                         \
            la0 = *(const uint4*)(abase + (c) * 32);                    \
            la1 = *(const uint4*)(abase + (c) * 32 + 8);                \
        } else {                                                        \
            la0 = make_uint4(0u, 0u, 0u, 0u);                           \
            la1 = make_uint4(0u, 0u, 0u, 0u);                           \
        }                                                               \
        const int pg_ = (c) * 16 + p2;                                  \
        const float* q1_ = v1 + ((size_t)pg_ * B + b) * R + rr;         \
        const float* q2_ = v2 + ((size_t)pg_ * B + b) * R + rr;         \
        lv1[0] = *(const float4*)(q1_ + 0);                             \
        lv1[1] = *(const float4*)(q1_ + 4);                             \
        lv2[0] = *(const float4*)(q2_ + 0);                             \
        lv2[1] = *(const float4*)(q2_ + 4);                             \
    } while (0)

    #define STAGE_WRITE(buf) do {                                       \
        *(uint4*)&As[buf][arow][ajh]     = la0;                         \
        *(uint4*)&As[buf][arow][ajh + 8] = la1;                         \
        const float* f1_ = (const float*)lv1;                           \
        const float* f2_ = (const float*)lv2;                           \
        _Pragma("unroll")                                               \
        for (int i_ = 0; i_ < 8; ++i_) {                                \
            unsigned pk_ = (unsigned)f2bf(f1_[i_]) |                    \
                           ((unsigned)f2bf(f2_[i_]) << 16);             \
            *(unsigned*)&Bs[buf][ro*8 + i_][p2*2] = pk_;                \
        }                                                               \
    } while (0)

    const int tb = wv * 32 + (lane & 15);
    const int ko = (lane >> 4) * 8;

    STAGE_LOAD(0);
    STAGE_WRITE(0);
    #pragma unroll
    for (int c = 0; c < 8; ++c) {
        const int buf = c & 1;
        if (c < 7) STAGE_LOAD(c + 1);
        __syncthreads();
        if (c <= 2 * wv + 1) {          // chunks beyond this are all-zero A
            bf16x8 a0 = *(const bf16x8*)&As[buf][tb][ko];
            bf16x8 a1 = *(const bf16x8*)&As[buf][tb + 16][ko];
            #pragma unroll
            for (int cf = 0; cf < 8; ++cf) {
                bf16x8 bb = *(const bf16x8*)&Bs[buf][cf*16 + (lane & 15)][ko];
                acc0[cf] = __builtin_amdgcn_mfma_f32_16x16x32_bf16(a0, bb, acc0[cf], 0, 0, 0);
                acc1[cf] = __builtin_amdgcn_mfma_f32_16x16x32_bf16(a1, bb, acc1[cf], 0, 0, 0);
            }
        }
        if (c < 7) STAGE_WRITE((c + 1) & 1);
    }

    // epilogue: D col = lane&15 (r), row = (lane>>4)*4 + i (t)
    const int dcol  = lane & 15;
    const int drow4 = (lane >> 4) * 4;
    #pragma unroll
    for (int cf = 0; cf < 8; ++cf) {
        const int rg = r0 + cf * 16 + dcol;
        #pragma unroll
        for (int i = 0; i < 4; ++i) {
            const int tg0 = wv * 32 + drow4 + i;
            const int tg1 = tg0 + 16;
            out[((size_t)tg0 * B + b) * R + rg] = acc0[cf][i];
            out[((size_t)tg1 * B + b) * R + rg] = acc1[cf][i];
        }
    }
    #undef STAGE_LOAD
    #undef STAGE_WRITE
}

extern "C" void kernel_launch(void* const* d_in, const int* in_sizes, int n_in,
                              void* d_out, int out_size, void* d_ws, size_t ws_size,
                              hipStream_t stream) {
    const float* u  = (const float*)d_in[0];
    const float* d1 = (const float*)d_in[1];
    const float* d2 = (const float*)d_in[2];
    const float* v1 = (const float*)d_in[3];
    const float* v2 = (const float*)d_in[4];
    float* out = (float*)d_out;
    ushort* w  = (ushort*)d_ws;          // 8.39 MB bf16

    weights<<<dim3(T), dim3(256), 0, stream>>>(u, d1, d2, w);
    // grid x = b (fastest): same-b r-tiles land on the same XCD (id % 8 == b % 8)
    gemm_mfma<<<dim3(B, R / 128), dim3(256), 0, stream>>>(w, v1, v2, out);
}